// Round 10
// baseline (1412.882 us; speedup 1.0000x reference)
//
#include <hip/hip_runtime.h>
#include <hip/hip_bf16.h>

#define N_ 1024
#define M_ 1152
#define L_ 32
#define NATSTRIDE (L_*M_)   // 36864
#define CONVK 129
#define OUTW 1024
#define NSTEP 31
#define K2_ 2304

typedef __attribute__((ext_vector_type(8))) short short8;
typedef __attribute__((ext_vector_type(4))) float f32x4;

__device__ __forceinline__ unsigned short f2bf(float f) {
    unsigned int u = __float_as_uint(f);
    u += 0x7FFFu + ((u >> 16) & 1u);   // round-to-nearest-even
    return (unsigned short)(u >> 16);
}
__device__ __forceinline__ float bf2f(unsigned short b) {
    return __uint_as_float(((unsigned int)b) << 16);
}

// Build Wcat bf16 [M_][K2_]: Wcat[m][k] = k<M_ ? convW[m][k][0] : convW[m][k-M_][1]
__global__ __launch_bounds__(256) void build_wcat(const float* __restrict__ convW,
                                                  unsigned short* __restrict__ wcat) {
    int idx = blockIdx.x * blockDim.x + threadIdx.x;
    if (idx >= M_ * K2_) return;
    int m = idx / K2_;
    int k = idx - m * K2_;
    float v = (k < M_) ? convW[(size_t)m * K2_ + 2 * k]
                       : convW[(size_t)m * K2_ + 2 * (k - M_) + 1];
    wcat[idx] = f2bf(v);
}

// h0 = bf16(NATree[:, L-1, :])
__global__ __launch_bounds__(256) void build_h0(const float* __restrict__ nat,
                                                unsigned short* __restrict__ h0) {
    int idx = blockIdx.x * blockDim.x + threadIdx.x;
    if (idx >= N_ * M_) return;
    int n = idx / M_;
    int m = idx - n * M_;
    h0[idx] = f2bf(nat[(size_t)n * NATSTRIDE + (size_t)(L_ - 1) * M_ + m]);
}

// rbf[t][n][m] = bf16(NATree[n][30-t][m])  for t = 0..30
__global__ __launch_bounds__(256) void build_rbf(const float* __restrict__ nat,
                                                 unsigned short* __restrict__ rbf) {
    int idx = blockIdx.x * blockDim.x + threadIdx.x;   // one thread per 8 elems
    if (idx >= NSTEP * N_ * M_ / 8) return;
    int o = idx * 8;
    int t = o / (N_ * M_);
    int rem = o - t * (N_ * M_);
    int n = rem / M_;
    int m = rem - n * M_;
    int l = (NSTEP - 1) - t;
    const float* s = nat + (size_t)n * NATSTRIDE + (size_t)l * M_ + m;
    f32x4 v0 = *(const f32x4*)(s);
    f32x4 v1 = *(const f32x4*)(s + 4);
    short8 tt;
    #pragma unroll
    for (int e = 0; e < 4; ++e) {
        tt[e]     = (short)f2bf(v0[e]);
        tt[4 + e] = (short)f2bf(v1[e]);
    }
    *(short8*)(rbf + o) = tt;
}

// ---------------- Fused step: hv = tanh([r_t, h] @ Wcat^T + b) + r_t ----------------
// 72 blocks = 8 rowgrps (128 rows, XCD-affine via bid%8) x 9 colgrps (128 cols).
// 4 waves (2x2 of 64x64), K=2304, BK=64 (36 iters), dbuf LDS + depth-2 register queue.
// Dense per-CU regime: traffic ~45 MB/step (vs 85 at 64x64 tiles), LDS-port-bound core.
#define F_BM 128
#define F_BN 128
#define F_BK 64
#define F_NT (K2_ / F_BK)   // 36
#define F_LDP 72

__global__ __launch_bounds__(256) void fused_step(
    const unsigned short* __restrict__ rbf_t,   // bf16 r_t rows [n][1152]
    const unsigned short* __restrict__ hin,     // bf16 h rows [n][1152]
    const unsigned short* __restrict__ wcat,    // bf16 [1152][2304] = [W0 | W1]
    const float* __restrict__ convb,
    const float* __restrict__ x,
    unsigned short* __restrict__ hout,
    float* __restrict__ resOut,
    int final_step)
{
    __shared__ __align__(16) unsigned short As[2][F_BM * F_LDP];
    __shared__ __align__(16) unsigned short Bs[2][F_BM * F_LDP];

    int tid = threadIdx.x;
    int lane = tid & 63;
    int w = tid >> 6;
    int wr = w >> 1, wc = w & 1;       // 2x2 waves, 64x64 each
    int bid = blockIdx.x;
    int rg = bid & 7;                  // rowgroup -> fixed XCD (h stays L2-local)
    int cg = bid >> 3;                 // colgroup 0..8
    int n0 = rg * F_BM;
    int m0 = cg * F_BN;
    int lr = lane & 15;
    int lg = lane >> 4;
    int lk = lg * 8;

    f32x4 acc[4][4] = {};

    auto loadA = [&](int it, short8 a[4]) {
        int kb = it * F_BK;
        const unsigned short* base = (kb < M_) ? rbf_t : hin;
        int ko = (kb < M_) ? kb : (kb - M_);
        #pragma unroll
        for (int i = 0; i < 4; ++i) {
            int chunk = i * 256 + tid;
            int row = chunk >> 3;
            int kc = (chunk & 7) * 8;
            a[i] = *(const short8*)(base + (size_t)(n0 + row) * M_ + ko + kc);
        }
    };
    auto loadB = [&](int it, short8 b[4]) {
        int kb = it * F_BK;
        #pragma unroll
        for (int i = 0; i < 4; ++i) {
            int chunk = i * 256 + tid;
            int row = chunk >> 3;
            int kc = (chunk & 7) * 8;
            b[i] = *(const short8*)(wcat + (size_t)(m0 + row) * K2_ + kb + kc);
        }
    };
    auto writeTile = [&](int buf, short8 a[4], short8 b[4]) {
        #pragma unroll
        for (int i = 0; i < 4; ++i) {
            int chunk = i * 256 + tid;
            int row = chunk >> 3;
            int kc = (chunk & 7) * 8;
            *(short8*)&As[buf][row * F_LDP + kc] = a[i];
            *(short8*)&Bs[buf][row * F_LDP + kc] = b[i];
        }
    };
    auto compute = [&](int buf) {
        #pragma unroll
        for (int ks = 0; ks < F_BK; ks += 32) {
            short8 af[4], bf_[4];
            #pragma unroll
            for (int mi = 0; mi < 4; ++mi)
                af[mi] = *(const short8*)&As[buf][(wr * 64 + mi * 16 + lr) * F_LDP + ks + lk];
            #pragma unroll
            for (int ni = 0; ni < 4; ++ni)
                bf_[ni] = *(const short8*)&Bs[buf][(wc * 64 + ni * 16 + lr) * F_LDP + ks + lk];
            #pragma unroll
            for (int mi = 0; mi < 4; ++mi)
                #pragma unroll
                for (int ni = 0; ni < 4; ++ni)
                    acc[mi][ni] = __builtin_amdgcn_mfma_f32_16x16x32_bf16(
                        af[mi], bf_[ni], acc[mi][ni], 0, 0, 0);
        }
    };

    // register queue: tile k lives in q[k&1]
    short8 q0A[4], q0B[4], q1A[4], q1B[4];
    loadA(0, q0A); loadB(0, q0B);
    writeTile(0, q0A, q0B);            // ds_write consumes regs at issue
    loadA(1, q1A); loadB(1, q1B);      // tile 1 -> q1
    loadA(2, q0A); loadB(2, q0B);      // tile 2 -> q0

    // epilogue operand prefetch (L2/L3 latency hides under the K-loop)
    float biasR[4];
    unsigned short rbfR[4][4][4];
    #pragma unroll
    for (int ni = 0; ni < 4; ++ni)
        biasR[ni] = convb[m0 + wc * 64 + ni * 16 + lr];
    #pragma unroll
    for (int mi = 0; mi < 4; ++mi)
        #pragma unroll
        for (int ni = 0; ni < 4; ++ni) {
            int mloc = m0 + wc * 64 + ni * 16 + lr;
            #pragma unroll
            for (int j = 0; j < 4; ++j) {
                int nloc = n0 + wr * 64 + mi * 16 + lg * 4 + j;
                rbfR[mi][ni][j] = rbf_t[(size_t)nloc * M_ + mloc];
            }
        }
    __syncthreads();

    int cur = 0;
    #pragma unroll 1
    for (int it2 = 0; it2 < F_NT; it2 += 2) {
        // even iter: next tile (it2+1, odd) sits in q1
        compute(cur);
        {
            writeTile(cur ^ 1, q1A, q1B);
            if (it2 + 3 < F_NT) { loadA(it2 + 3, q1A); loadB(it2 + 3, q1B); }
            __syncthreads();
            cur ^= 1;
        }
        // odd iter: next tile (it2+2, even) sits in q0
        compute(cur);
        if (it2 + 2 < F_NT) {
            writeTile(cur ^ 1, q0A, q0B);
            if (it2 + 4 < F_NT) { loadA(it2 + 4, q0A); loadB(it2 + 4, q0B); }
            __syncthreads();
            cur ^= 1;
        }
    }

    // epilogue
    #pragma unroll
    for (int mi = 0; mi < 4; ++mi) {
        #pragma unroll
        for (int ni = 0; ni < 4; ++ni) {
            int mloc = m0 + wc * 64 + ni * 16 + lr;
            #pragma unroll
            for (int j = 0; j < 4; ++j) {
                int nloc = n0 + wr * 64 + mi * 16 + lg * 4 + j;
                float pre = acc[mi][ni][j] + biasR[ni];
                float hv = tanhf(pre) + bf2f(rbfR[mi][ni][j]);
                if (final_step) {
                    resOut[(size_t)nloc * M_ + mloc] = tanhf(tanhf(hv) + x[(size_t)nloc * M_ + mloc]);
                } else {
                    hout[(size_t)nloc * M_ + mloc] = f2bf(hv);
                }
            }
        }
    }
}

// out[n][j] = conv2b + sum_k res[n][j+k] * conv2W[k]
__global__ __launch_bounds__(256) void conv_out_kernel(
    const float* __restrict__ res, const float* __restrict__ w2,
    const float* __restrict__ b2, float* __restrict__ out)
{
    __shared__ float row[M_];
    __shared__ float wk[CONVK];
    int n = blockIdx.x;
    int tid = threadIdx.x;
    for (int i = tid; i < M_; i += 256) row[i] = res[(size_t)n * M_ + i];
    if (tid < CONVK) wk[tid] = w2[tid];
    __syncthreads();
    float b = b2[0];
    int j0 = tid * 4;
    float s0 = b, s1 = b, s2 = b, s3 = b;
    float r0 = row[j0], r1 = row[j0 + 1], r2 = row[j0 + 2], r3 = row[j0 + 3];
    for (int k = 0; k < CONVK; ++k) {
        float wv = wk[k];
        s0 += r0 * wv; s1 += r1 * wv; s2 += r2 * wv; s3 += r3 * wv;
        if (k < CONVK - 1) { r0 = r1; r1 = r2; r2 = r3; r3 = row[j0 + 4 + k]; }
    }
    float* o = out + (size_t)n * OUTW + j0;
    o[0] = s0; o[1] = s1; o[2] = s2; o[3] = s3;
}

extern "C" void kernel_launch(void* const* d_in, const int* in_sizes, int n_in,
                              void* d_out, int out_size, void* d_ws, size_t ws_size,
                              hipStream_t stream) {
    const float* NATree = (const float*)d_in[0];
    const float* x      = (const float*)d_in[1];
    const float* convW  = (const float*)d_in[2];
    const float* convb  = (const float*)d_in[3];
    const float* conv2W = (const float*)d_in[4];
    const float* conv2b = (const float*)d_in[5];
    float* out = (float*)d_out;

    char* ws = (char*)d_ws;
    size_t off = 0;
    auto alloc = [&](size_t bytes) {
        void* p = ws + off;
        off = (off + bytes + 255) & ~(size_t)255;
        return p;
    };
    unsigned short* wcat = (unsigned short*)alloc((size_t)M_ * K2_ * 2);
    unsigned short* hA   = (unsigned short*)alloc((size_t)N_ * M_ * 2);
    unsigned short* hB   = (unsigned short*)alloc((size_t)N_ * M_ * 2);
    unsigned short* rbf  = (unsigned short*)alloc((size_t)NSTEP * N_ * M_ * 2);
    float*          res  = (float*)alloc((size_t)N_ * M_ * 4);

    build_wcat<<<(M_ * K2_ + 255) / 256, 256, 0, stream>>>(convW, wcat);
    build_h0<<<(N_ * M_ + 255) / 256, 256, 0, stream>>>(NATree, hA);
    build_rbf<<<(NSTEP * N_ * M_ / 8 + 255) / 256, 256, 0, stream>>>(NATree, rbf);

    // Sequential fused chain: 31 x (GEMM K=2304 + epilogue), 72 blocks each
    const unsigned short* hin = hA;
    unsigned short* hout = hB;
    for (int t = 0; t < NSTEP; ++t) {
        int fin = (t == NSTEP - 1) ? 1 : 0;
        fused_step<<<72, 256, 0, stream>>>(
            rbf + (size_t)t * N_ * M_, hin, wcat, convb, x, hout, res, fin);
        unsigned short* tmp = hout;
        hout = (unsigned short*)hin;
        hin = tmp;
    }

    conv_out_kernel<<<1024, 256, 0, stream>>>(res, conv2W, conv2b, out);
}